// Round 5
// baseline (582.997 us; speedup 1.0000x reference)
//
#include <hip/hip_runtime.h>

typedef unsigned short u16;
typedef unsigned short u16x8 __attribute__((ext_vector_type(8)));
typedef __bf16         bf16x8 __attribute__((ext_vector_type(8)));
typedef float          f32x4  __attribute__((ext_vector_type(4)));

#define DIM 512
#define LTOK 25088   // 8 * 56 * 56

__device__ __forceinline__ float bf2f(u16 u) {
  union { unsigned int i; float f; } c; c.i = ((unsigned int)u) << 16; return c.f;
}
__device__ __forceinline__ u16 f2bf(float f) {
  union { float f; unsigned int i; } c; c.f = f;
  unsigned int i = c.i;
  return (u16)((i + 0x7FFFu + ((i >> 16) & 1u)) >> 16);
}
__device__ __forceinline__ float gelu_tanh(float x) {
  float x3 = x * x * x;
  return 0.5f * x * (1.0f + tanhf(0.7978845608028654f * (x + 0.044715f * x3)));
}
// async global->LDS, 16B per lane; LDS dest must be wave-uniform
__device__ __forceinline__ void gload16(const u16* g, u16* l) {
  __builtin_amdgcn_global_load_lds(
      (__attribute__((address_space(1))) void*)(u16*)g,
      (__attribute__((address_space(3))) void*)l,
      16, 0, 0);
}
// window-major row -> natural token index (same map for partition source and reverse dest)
__device__ __forceinline__ int rowToToken(int row) {
  int win = row / 49, t = row - win * 49;
  int b = win >> 6, wi = win & 63;
  int hr = (wi >> 3) * 7 + t / 7;
  int wr = (wi & 7) * 7 + t % 7;
  int hs = hr + 3; if (hs >= 56) hs -= 56;
  int ws2 = wr + 3; if (ws2 >= 56) ws2 -= 56;
  return b * 3136 + hs * 56 + ws2;
}

// ---------------- LN1: f32 in (natural order, rolled+permuted source), bf16 out (window-major) ----
__global__ __launch_bounds__(256) void ln1_kernel(const float* __restrict__ x,
    const float* __restrict__ w, const float* __restrict__ b, u16* __restrict__ out) {
  int r = blockIdx.x * 4 + (threadIdx.x >> 6);   // output row, window-major
  int lane = threadIdx.x & 63;
  int tok = rowToToken(r);
  const float* src = x + (size_t)tok * DIM + lane * 8;
  float v[8]; float s = 0.f, ss = 0.f;
  f32x4 v0 = *(const f32x4*)(src);
  f32x4 v1 = *(const f32x4*)(src + 4);
  #pragma unroll
  for (int j = 0; j < 4; ++j) { v[j] = v0[j]; v[j + 4] = v1[j]; }
  #pragma unroll
  for (int j = 0; j < 8; ++j) { s += v[j]; ss += v[j] * v[j]; }
  #pragma unroll
  for (int off = 32; off > 0; off >>= 1) { s += __shfl_xor(s, off); ss += __shfl_xor(ss, off); }
  float mean = s * (1.0f / 512.0f);
  float var  = ss * (1.0f / 512.0f) - mean * mean;
  float rstd = rsqrtf(var + 1e-5f);
  f32x4 w0 = *(const f32x4*)(w + lane * 8), w1 = *(const f32x4*)(w + lane * 8 + 4);
  f32x4 b0 = *(const f32x4*)(b + lane * 8), b1 = *(const f32x4*)(b + lane * 8 + 4);
  u16x8 o;
  #pragma unroll
  for (int j = 0; j < 4; ++j) {
    o[j]     = f2bf((v[j]     - mean) * rstd * w0[j] + b0[j]);
    o[j + 4] = f2bf((v[j + 4] - mean) * rstd * w1[j] + b1[j]);
  }
  *(u16x8*)(out + (size_t)r * DIM + lane * 8) = o;
}

// ---------------- LN2: f32 in (natural order), bf16 out ----------------
__global__ __launch_bounds__(256) void ln2_kernel(const float* __restrict__ x2,
    const float* __restrict__ w, const float* __restrict__ b, u16* __restrict__ out) {
  int r = blockIdx.x * 4 + (threadIdx.x >> 6);
  int lane = threadIdx.x & 63;
  const float* src = x2 + (size_t)r * DIM + lane * 8;
  float v[8]; float s = 0.f, ss = 0.f;
  f32x4 v0 = *(const f32x4*)(src);
  f32x4 v1 = *(const f32x4*)(src + 4);
  #pragma unroll
  for (int j = 0; j < 4; ++j) { v[j] = v0[j]; v[j + 4] = v1[j]; }
  #pragma unroll
  for (int j = 0; j < 8; ++j) { s += v[j]; ss += v[j] * v[j]; }
  #pragma unroll
  for (int off = 32; off > 0; off >>= 1) { s += __shfl_xor(s, off); ss += __shfl_xor(ss, off); }
  float mean = s * (1.0f / 512.0f);
  float var  = ss * (1.0f / 512.0f) - mean * mean;
  float rstd = rsqrtf(var + 1e-5f);
  f32x4 w0 = *(const f32x4*)(w + lane * 8), w1 = *(const f32x4*)(w + lane * 8 + 4);
  f32x4 b0 = *(const f32x4*)(b + lane * 8), b1 = *(const f32x4*)(b + lane * 8 + 4);
  u16x8 o;
  #pragma unroll
  for (int j = 0; j < 4; ++j) {
    o[j]     = f2bf((v[j]     - mean) * rstd * w0[j] + b0[j]);
    o[j + 4] = f2bf((v[j + 4] - mean) * rstd * w1[j] + b1[j]);
  }
  *(u16x8*)(out + (size_t)r * DIM + lane * 8) = o;
}

// ---------------- weight transpose+cast: f32 (K,N) -> bf16 (N,K) ----------------
__global__ __launch_bounds__(256) void transpose_kernel(const float* __restrict__ in,
    u16* __restrict__ out, int K, int N) {
  __shared__ u16 tile[32][33];
  int tx = threadIdx.x & 31, ty = threadIdx.x >> 5;
  int n0 = blockIdx.x * 32, k0 = blockIdx.y * 32;
  #pragma unroll
  for (int r = 0; r < 4; ++r) {
    int kr = ty + r * 8;
    tile[kr][tx] = f2bf(in[(size_t)(k0 + kr) * N + n0 + tx]);
  }
  __syncthreads();
  #pragma unroll
  for (int r = 0; r < 4; ++r) {
    int nr = ty + r * 8;
    out[(size_t)(n0 + nr) * K + k0 + tx] = tile[tx][nr];
  }
}

// ---------------- GEMM: C(MxN) = A(MxK) * Bt(NxK)^T + bias(f32), fused epilogues ----------------
// MODE 0: -> bf16 row-major (qkv).
// MODE 1: window-reverse, + f32 residual (x), -> f32 (x2 in d_out).
// MODE 2: gelu -> bf16 (fc1).
// MODE 3: + f32 residual (x2), -> f32 (final out; outp may alias resF, same-index RMW).
template<int MODE, int N, int KD>
__global__ __launch_bounds__(256) void gemm_kernel(
    const u16* __restrict__ A, const u16* __restrict__ Bt,
    const float* __restrict__ bias, void* outp,
    const float* resF) {
  __shared__ __align__(16) u16 lA[128 * 64];
  __shared__ __align__(16) u16 lB[128 * 64];
  int tid = threadIdx.x;
  int lane = tid & 63, wid = tid >> 6;
  int wm = wid >> 1, wn = wid & 1;
  int m0 = blockIdx.x * 128, n0 = blockIdx.y * 128;
  int l15 = lane & 15, l4 = lane >> 4;
  f32x4 acc[4][4];
  #pragma unroll
  for (int i = 0; i < 4; ++i)
    #pragma unroll
    for (int j = 0; j < 4; ++j) acc[i][j] = (f32x4){0.f, 0.f, 0.f, 0.f};

  for (int k0 = 0; k0 < KD; k0 += 64) {
    #pragma unroll
    for (int is = 0; is < 4; ++is) {
      int e = is * 2048 + tid * 8;          // element within 128x64 tile (row-major, k inner)
      int mm = e >> 6, kk = e & 63;
      gload16(A  + (size_t)(m0 + mm) * KD + k0 + kk, &lA[is * 2048 + wid * 512]);
      gload16(Bt + (size_t)(n0 + mm) * KD + k0 + kk, &lB[is * 2048 + wid * 512]);
    }
    __syncthreads();
    #pragma unroll
    for (int ks = 0; ks < 2; ++ks) {
      bf16x8 af[4], bfv[4];
      #pragma unroll
      for (int i = 0; i < 4; ++i)
        af[i] = *(const bf16x8*)&lA[(wm * 64 + i * 16 + l15) * 64 + ks * 32 + l4 * 8];
      #pragma unroll
      for (int j = 0; j < 4; ++j)
        bfv[j] = *(const bf16x8*)&lB[(wn * 64 + j * 16 + l15) * 64 + ks * 32 + l4 * 8];
      #pragma unroll
      for (int i = 0; i < 4; ++i)
        #pragma unroll
        for (int j = 0; j < 4; ++j)
          acc[i][j] = __builtin_amdgcn_mfma_f32_16x16x32_bf16(af[i], bfv[j], acc[i][j], 0, 0, 0);
    }
    __syncthreads();
  }

  #pragma unroll
  for (int i = 0; i < 4; ++i) {
    #pragma unroll
    for (int j = 0; j < 4; ++j) {
      int col = n0 + wn * 64 + j * 16 + l15;
      float bcol = bias[col];
      #pragma unroll
      for (int r = 0; r < 4; ++r) {
        int row = m0 + wm * 64 + i * 16 + l4 * 4 + r;
        float v = acc[i][j][r] + bcol;
        if constexpr (MODE == 0) {
          ((u16*)outp)[(size_t)row * N + col] = f2bf(v);
        } else if constexpr (MODE == 1) {
          int tok = rowToToken(row);
          size_t idx = (size_t)tok * DIM + col;
          ((float*)outp)[idx] = v + resF[idx];
        } else if constexpr (MODE == 2) {
          ((u16*)outp)[(size_t)row * N + col] = f2bf(gelu_tanh(v));
        } else {  // MODE 3
          size_t idx = (size_t)row * N + col;
          ((float*)outp)[idx] = v + resF[idx];
        }
      }
    }
  }
}

// ---------------- window attention: 1 wave per (window, head), bf16 qkv in, bf16 out ----------------
typedef unsigned int u32x4 __attribute__((ext_vector_type(4)));
__global__ __launch_bounds__(64) void attn_kernel(const u16* __restrict__ qkv,
                                                  u16* __restrict__ out) {
  int blk = blockIdx.x;
  int win = blk >> 4, head = blk & 15;
  int wi = win & 63;
  __shared__ __align__(16) u16 kls[49 * 32];
  __shared__ __align__(16) u16 vls[49 * 32];
  __shared__ int codes[49];
  int lane = threadIdx.x;
  size_t base = (size_t)win * 49 * 1536 + head * 32;

  for (int e = lane; e < 196; e += 64) {        // 49 tokens * 4 vec8-chunks
    int t = e >> 2, d0 = (e & 3) * 8;
    *(u32x4*)&kls[t * 32 + d0] = *(const u32x4*)(qkv + base + (size_t)t * 1536 + 512  + d0);
    *(u32x4*)&vls[t * 32 + d0] = *(const u32x4*)(qkv + base + (size_t)t * 1536 + 1024 + d0);
  }
  if (lane < 49) {
    int hr = (wi >> 3) * 7 + lane / 7;
    int wr = (wi & 7) * 7 + lane % 7;
    int rh = (hr < 49) ? 0 : (hr < 53 ? 1 : 2);
    int rw = (wr < 49) ? 0 : (wr < 53 ? 1 : 2);
    codes[lane] = rh * 3 + rw;
  }
  float q[32];
  if (lane < 49) {
    const float scale = 0.17677669529663687f;   // 1/sqrt(32)
    #pragma unroll
    for (int d0 = 0; d0 < 32; d0 += 8) {
      u16x8 raw = *(const u16x8*)(qkv + base + (size_t)lane * 1536 + d0);
      #pragma unroll
      for (int j = 0; j < 8; ++j) q[d0 + j] = bf2f(raw[j]) * scale;
    }
  }
  __syncthreads();
  if (lane < 49) {
    int cq = codes[lane];
    float p[49];
    float mx = -1e30f;
    #pragma unroll
    for (int t = 0; t < 49; ++t) {
      float s_ = 0.f;
      #pragma unroll
      for (int d0 = 0; d0 < 32; d0 += 8) {
        u16x8 kr = *(const u16x8*)&kls[t * 32 + d0];
        #pragma unroll
        for (int j = 0; j < 8; ++j) s_ += q[d0 + j] * bf2f(kr[j]);
      }
      s_ = (codes[t] == cq) ? s_ : -1e30f;
      p[t] = s_;
      mx = fmaxf(mx, s_);
    }
    float sum = 0.f;
    #pragma unroll
    for (int t = 0; t < 49; ++t) { float e_ = __expf(p[t] - mx); p[t] = e_; sum += e_; }
    float inv = 1.0f / sum;
    float o[32];
    #pragma unroll
    for (int d = 0; d < 32; ++d) o[d] = 0.f;
    #pragma unroll
    for (int t = 0; t < 49; ++t) {
      float pt = p[t] * inv;
      #pragma unroll
      for (int d0 = 0; d0 < 32; d0 += 8) {
        u16x8 vr = *(const u16x8*)&vls[t * 32 + d0];
        #pragma unroll
        for (int j = 0; j < 8; ++j) o[d0 + j] += pt * bf2f(vr[j]);
      }
    }
    #pragma unroll
    for (int d0 = 0; d0 < 32; d0 += 8) {
      u16x8 ov;
      #pragma unroll
      for (int j = 0; j < 8; ++j) ov[j] = f2bf(o[d0 + j]);
      *(u16x8*)(out + ((size_t)win * 49 + lane) * DIM + head * 32 + d0) = ov;
    }
  }
}

extern "C" void kernel_launch(void* const* d_in, const int* in_sizes, int n_in,
                              void* d_out, int out_size, void* d_ws, size_t ws_size,
                              hipStream_t stream) {
  const float* x     = (const float*)d_in[0];
  const float* ln1w  = (const float*)d_in[1];
  const float* ln1b  = (const float*)d_in[2];
  const float* qkvw  = (const float*)d_in[3];
  const float* qkvb  = (const float*)d_in[4];
  const float* projw = (const float*)d_in[5];
  const float* projb = (const float*)d_in[6];
  const float* ln2w  = (const float*)d_in[7];
  const float* ln2b  = (const float*)d_in[8];
  const float* fc1w  = (const float*)d_in[9];
  const float* fc1b  = (const float*)d_in[10];
  const float* fc2w  = (const float*)d_in[11];
  const float* fc2b  = (const float*)d_in[12];
  float* outF = (float*)d_out;

  u16* wsu     = (u16*)d_ws;
  u16* qkv_wt  = wsu;                         // 512*1536 bf16
  u16* proj_wt = qkv_wt  + 512 * 1536;        // 512*512
  u16* fc1_wt  = proj_wt + 512 * 512;         // 1024 rows x 512 (N,K)
  u16* fc2_wt  = fc1_wt  + 512 * 1024;        // 512 rows x 1024
  u16* xw      = fc2_wt  + 1024 * 512;        // LTOK*512 bf16 (LN1 out; later attnO; later LN2 out)
  u16* qkvB    = xw + (size_t)LTOK * 512;     // LTOK*1536 bf16 (later fc1 out z1)
  u16* attnO   = xw;                          // alias: xw dead after qkv GEMM
  u16* z_in    = xw;                          // alias: attnO dead after proj GEMM
  u16* z1      = qkvB;                        // alias: qkvB dead after attn
  float* x2    = outF;                        // f32 residual stream lives in d_out

  transpose_kernel<<<dim3(1536 / 32, 512 / 32), 256, 0, stream>>>(qkvw, qkv_wt, 512, 1536);
  transpose_kernel<<<dim3(512 / 32, 512 / 32),  256, 0, stream>>>(projw, proj_wt, 512, 512);
  transpose_kernel<<<dim3(1024 / 32, 512 / 32), 256, 0, stream>>>(fc1w, fc1_wt, 512, 1024);
  transpose_kernel<<<dim3(512 / 32, 1024 / 32), 256, 0, stream>>>(fc2w, fc2_wt, 1024, 512);

  ln1_kernel<<<LTOK / 4, 256, 0, stream>>>(x, ln1w, ln1b, xw);

  gemm_kernel<0, 1536, 512><<<dim3(196, 12), 256, 0, stream>>>(xw, qkv_wt, qkvb, qkvB, nullptr);

  attn_kernel<<<512 * 16, 64, 0, stream>>>(qkvB, attnO);

  gemm_kernel<1, 512, 512><<<dim3(196, 4), 256, 0, stream>>>(attnO, proj_wt, projb, x2, x);

  ln2_kernel<<<LTOK / 4, 256, 0, stream>>>(x2, ln2w, ln2b, z_in);

  gemm_kernel<2, 1024, 512><<<dim3(196, 8), 256, 0, stream>>>(z_in, fc1_wt, fc1b, z1, nullptr);

  gemm_kernel<3, 512, 1024><<<dim3(196, 4), 256, 0, stream>>>(z1, fc2_wt, fc2b, outF, x2);
}

// Round 6
// 469.658 us; speedup vs baseline: 1.2413x; 1.2413x over previous
//
#include <hip/hip_runtime.h>

typedef unsigned short u16;
typedef unsigned short u16x8 __attribute__((ext_vector_type(8)));
typedef __bf16         bf16x8 __attribute__((ext_vector_type(8)));
typedef float          f32x4  __attribute__((ext_vector_type(4)));

#define DIM 512
#define LTOK 25088   // 8 * 56 * 56

__device__ __forceinline__ float bf2f(u16 u) {
  union { unsigned int i; float f; } c; c.i = ((unsigned int)u) << 16; return c.f;
}
__device__ __forceinline__ u16 f2bf(float f) {
  union { float f; unsigned int i; } c; c.f = f;
  unsigned int i = c.i;
  return (u16)((i + 0x7FFFu + ((i >> 16) & 1u)) >> 16);
}
__device__ __forceinline__ float gelu_tanh(float x) {
  float x3 = x * x * x;
  return 0.5f * x * (1.0f + tanhf(0.7978845608028654f * (x + 0.044715f * x3)));
}
// async global->LDS, 16B per lane; LDS dest must be wave-uniform
__device__ __forceinline__ void gload16(const u16* g, u16* l) {
  __builtin_amdgcn_global_load_lds(
      (__attribute__((address_space(1))) void*)(u16*)g,
      (__attribute__((address_space(3))) void*)l,
      16, 0, 0);
}
// window-major row -> natural token index (same map for partition source and reverse dest)
__device__ __forceinline__ int rowToToken(int row) {
  int win = row / 49, t = row - win * 49;
  int b = win >> 6, wi = win & 63;
  int hr = (wi >> 3) * 7 + t / 7;
  int wr = (wi & 7) * 7 + t % 7;
  int hs = hr + 3; if (hs >= 56) hs -= 56;
  int ws2 = wr + 3; if (ws2 >= 56) ws2 -= 56;
  return b * 3136 + hs * 56 + ws2;
}

// ---------------- LN1: f32 in (natural order, rolled+permuted source), bf16 out (window-major) ----
__global__ __launch_bounds__(256) void ln1_kernel(const float* __restrict__ x,
    const float* __restrict__ w, const float* __restrict__ b, u16* __restrict__ out) {
  int r = blockIdx.x * 4 + (threadIdx.x >> 6);   // output row, window-major
  int lane = threadIdx.x & 63;
  int tok = rowToToken(r);
  const float* src = x + (size_t)tok * DIM + lane * 8;
  float v[8]; float s = 0.f, ss = 0.f;
  f32x4 v0 = *(const f32x4*)(src);
  f32x4 v1 = *(const f32x4*)(src + 4);
  #pragma unroll
  for (int j = 0; j < 4; ++j) { v[j] = v0[j]; v[j + 4] = v1[j]; }
  #pragma unroll
  for (int j = 0; j < 8; ++j) { s += v[j]; ss += v[j] * v[j]; }
  #pragma unroll
  for (int off = 32; off > 0; off >>= 1) { s += __shfl_xor(s, off); ss += __shfl_xor(ss, off); }
  float mean = s * (1.0f / 512.0f);
  float var  = ss * (1.0f / 512.0f) - mean * mean;
  float rstd = rsqrtf(var + 1e-5f);
  f32x4 w0 = *(const f32x4*)(w + lane * 8), w1 = *(const f32x4*)(w + lane * 8 + 4);
  f32x4 b0 = *(const f32x4*)(b + lane * 8), b1 = *(const f32x4*)(b + lane * 8 + 4);
  u16x8 o;
  #pragma unroll
  for (int j = 0; j < 4; ++j) {
    o[j]     = f2bf((v[j]     - mean) * rstd * w0[j] + b0[j]);
    o[j + 4] = f2bf((v[j + 4] - mean) * rstd * w1[j] + b1[j]);
  }
  *(u16x8*)(out + (size_t)r * DIM + lane * 8) = o;
}

// ---------------- LN2: f32 in (natural order), bf16 out ----------------
__global__ __launch_bounds__(256) void ln2_kernel(const float* __restrict__ x2,
    const float* __restrict__ w, const float* __restrict__ b, u16* __restrict__ out) {
  int r = blockIdx.x * 4 + (threadIdx.x >> 6);
  int lane = threadIdx.x & 63;
  const float* src = x2 + (size_t)r * DIM + lane * 8;
  float v[8]; float s = 0.f, ss = 0.f;
  f32x4 v0 = *(const f32x4*)(src);
  f32x4 v1 = *(const f32x4*)(src + 4);
  #pragma unroll
  for (int j = 0; j < 4; ++j) { v[j] = v0[j]; v[j + 4] = v1[j]; }
  #pragma unroll
  for (int j = 0; j < 8; ++j) { s += v[j]; ss += v[j] * v[j]; }
  #pragma unroll
  for (int off = 32; off > 0; off >>= 1) { s += __shfl_xor(s, off); ss += __shfl_xor(ss, off); }
  float mean = s * (1.0f / 512.0f);
  float var  = ss * (1.0f / 512.0f) - mean * mean;
  float rstd = rsqrtf(var + 1e-5f);
  f32x4 w0 = *(const f32x4*)(w + lane * 8), w1 = *(const f32x4*)(w + lane * 8 + 4);
  f32x4 b0 = *(const f32x4*)(b + lane * 8), b1 = *(const f32x4*)(b + lane * 8 + 4);
  u16x8 o;
  #pragma unroll
  for (int j = 0; j < 4; ++j) {
    o[j]     = f2bf((v[j]     - mean) * rstd * w0[j] + b0[j]);
    o[j + 4] = f2bf((v[j + 4] - mean) * rstd * w1[j] + b1[j]);
  }
  *(u16x8*)(out + (size_t)r * DIM + lane * 8) = o;
}

// ---------------- weight transpose+cast: f32 (K,N) -> bf16 (N,K) ----------------
__global__ __launch_bounds__(256) void transpose_kernel(const float* __restrict__ in,
    u16* __restrict__ out, int K, int N) {
  __shared__ u16 tile[32][33];
  int tx = threadIdx.x & 31, ty = threadIdx.x >> 5;
  int n0 = blockIdx.x * 32, k0 = blockIdx.y * 32;
  #pragma unroll
  for (int r = 0; r < 4; ++r) {
    int kr = ty + r * 8;
    tile[kr][tx] = f2bf(in[(size_t)(k0 + kr) * N + n0 + tx]);
  }
  __syncthreads();
  #pragma unroll
  for (int r = 0; r < 4; ++r) {
    int nr = ty + r * 8;
    out[(size_t)(n0 + nr) * K + k0 + tx] = tile[tx][nr];
  }
}

// ---------------- GEMM: C(MxN) = A(MxK) * Bt(NxK)^T + bias(f32), fused epilogues ----------------
// MODE 0: -> bf16 row-major (qkv).
// MODE 1: window-reverse, + f32 residual (x), -> f32 (x2 in d_out).
// MODE 2: gelu -> bf16 (fc1).
// MODE 3: + f32 residual (x2), -> f32 (final out; outp may alias resF, same-index RMW).
template<int MODE, int N, int KD>
__global__ __launch_bounds__(256) void gemm_kernel(
    const u16* __restrict__ A, const u16* __restrict__ Bt,
    const float* __restrict__ bias, void* outp,
    const float* resF) {
  __shared__ __align__(16) u16 lA[128 * 64];
  __shared__ __align__(16) u16 lB[128 * 64];
  int tid = threadIdx.x;
  int lane = tid & 63, wid = tid >> 6;
  int wm = wid >> 1, wn = wid & 1;
  int m0 = blockIdx.x * 128, n0 = blockIdx.y * 128;
  int l15 = lane & 15, l4 = lane >> 4;
  f32x4 acc[4][4];
  #pragma unroll
  for (int i = 0; i < 4; ++i)
    #pragma unroll
    for (int j = 0; j < 4; ++j) acc[i][j] = (f32x4){0.f, 0.f, 0.f, 0.f};

  for (int k0 = 0; k0 < KD; k0 += 64) {
    #pragma unroll
    for (int is = 0; is < 4; ++is) {
      int e = is * 2048 + tid * 8;          // element within 128x64 tile (row-major, k inner)
      int mm = e >> 6, kk = e & 63;
      gload16(A  + (size_t)(m0 + mm) * KD + k0 + kk, &lA[is * 2048 + wid * 512]);
      gload16(Bt + (size_t)(n0 + mm) * KD + k0 + kk, &lB[is * 2048 + wid * 512]);
    }
    __syncthreads();
    #pragma unroll
    for (int ks = 0; ks < 2; ++ks) {
      bf16x8 af[4], bfv[4];
      #pragma unroll
      for (int i = 0; i < 4; ++i)
        af[i] = *(const bf16x8*)&lA[(wm * 64 + i * 16 + l15) * 64 + ks * 32 + l4 * 8];
      #pragma unroll
      for (int j = 0; j < 4; ++j)
        bfv[j] = *(const bf16x8*)&lB[(wn * 64 + j * 16 + l15) * 64 + ks * 32 + l4 * 8];
      #pragma unroll
      for (int i = 0; i < 4; ++i)
        #pragma unroll
        for (int j = 0; j < 4; ++j)
          acc[i][j] = __builtin_amdgcn_mfma_f32_16x16x32_bf16(af[i], bfv[j], acc[i][j], 0, 0, 0);
    }
    __syncthreads();
  }

  #pragma unroll
  for (int i = 0; i < 4; ++i) {
    #pragma unroll
    for (int j = 0; j < 4; ++j) {
      int col = n0 + wn * 64 + j * 16 + l15;
      float bcol = bias[col];
      #pragma unroll
      for (int r = 0; r < 4; ++r) {
        int row = m0 + wm * 64 + i * 16 + l4 * 4 + r;
        float v = acc[i][j][r] + bcol;
        if constexpr (MODE == 0) {
          ((u16*)outp)[(size_t)row * N + col] = f2bf(v);
        } else if constexpr (MODE == 1) {
          int tok = rowToToken(row);
          size_t idx = (size_t)tok * DIM + col;
          ((float*)outp)[idx] = v + resF[idx];
        } else if constexpr (MODE == 2) {
          ((u16*)outp)[(size_t)row * N + col] = f2bf(gelu_tanh(v));
        } else {  // MODE 3
          size_t idx = (size_t)row * N + col;
          ((float*)outp)[idx] = v + resF[idx];
        }
      }
    }
  }
}

// ---------------- MFMA window attention: 1 block per window, 4 waves, 4 heads/wave ----------------
// Q,K frags loaded straight from global (both [tok][hd] = A-rows/B^T-rows idiom).
// V frags gathered 2B/lane (32B-coalesced per l4 group), issued before QK^T.
// P round-trips through wave-private LDS (stride 72 u16 -> 2-way conflicts only).
__global__ __launch_bounds__(256) void attn_kernel(const u16* __restrict__ qkv,
                                                   u16* __restrict__ out) {
  int win = blockIdx.x;
  int wi = win & 63;
  int tid = threadIdx.x, lane = tid & 63, wid = tid >> 6;
  int l15 = lane & 15, l4 = lane >> 4;
  __shared__ int codes[49];
  __shared__ __align__(16) u16 plds[4][64 * 72];
  if (tid < 49) {
    int hr = (wi >> 3) * 7 + tid / 7;
    int wr = (wi & 7) * 7 + tid % 7;
    int rh = (hr < 49) ? 0 : (hr < 53 ? 1 : 2);
    int rw = (wr < 49) ? 0 : (wr < 53 ? 1 : 2);
    codes[tid] = rh * 3 + rw;
  }
  __syncthreads();
  int ck[4], cq[4][4];
  #pragma unroll
  for (int j = 0; j < 4; ++j) {
    int c = 16 * j + l15;
    ck[j] = (c < 49) ? codes[c] : -1;
  }
  #pragma unroll
  for (int i = 0; i < 4; ++i)
    #pragma unroll
    for (int r = 0; r < 4; ++r) {
      int row = 16 * i + 4 * l4 + r;
      cq[i][r] = codes[row < 49 ? row : 48];
    }
  size_t wbase = (size_t)win * 49 * 1536;
  u16* pw = plds[wid];
  const float scale = 0.17677669529663687f;   // 1/sqrt(32)

  for (int hh = 0; hh < 4; ++hh) {
    int head = wid * 4 + hh;
    size_t hoff = wbase + (size_t)head * 32;

    // ---- V fragments first (latency hidden under QK^T) ----
    bf16x8 vf[2][2];
    #pragma unroll
    for (int ks = 0; ks < 2; ++ks)
      #pragma unroll
      for (int jn = 0; jn < 2; ++jn) {
        u16x8 tmp;
        #pragma unroll
        for (int j = 0; j < 8; ++j) {
          int tok = ks * 32 + l4 * 8 + j; tok = tok < 49 ? tok : 48;
          tmp[j] = qkv[hoff + (size_t)tok * 1536 + 1024 + jn * 16 + l15];
        }
        vf[ks][jn] = __builtin_bit_cast(bf16x8, tmp);
      }

    // ---- Q/K fragments (direct 16B global loads) ----
    bf16x8 qf[4], kf[4];
    #pragma unroll
    for (int i = 0; i < 4; ++i) {
      int tr = 16 * i + l15; tr = tr < 49 ? tr : 48;
      qf[i] = *(const bf16x8*)(qkv + hoff + (size_t)tr * 1536 + l4 * 8);
      kf[i] = *(const bf16x8*)(qkv + hoff + (size_t)tr * 1536 + 512 + l4 * 8);
    }

    // ---- S = Q K^T : 16 MFMA ----
    f32x4 acc[4][4];
    #pragma unroll
    for (int i = 0; i < 4; ++i)
      #pragma unroll
      for (int j = 0; j < 4; ++j) acc[i][j] = (f32x4){0.f, 0.f, 0.f, 0.f};
    #pragma unroll
    for (int i = 0; i < 4; ++i)
      #pragma unroll
      for (int j = 0; j < 4; ++j)
        acc[i][j] = __builtin_amdgcn_mfma_f32_16x16x32_bf16(qf[i], kf[j], acc[i][j], 0, 0, 0);

    // ---- mask + softmax (row = 16i+4*l4+r across lanes l15 x regs j) + P -> LDS ----
    #pragma unroll
    for (int i = 0; i < 4; ++i) {
      #pragma unroll
      for (int r = 0; r < 4; ++r) {
        float s0[4];
        float m = -1e30f;
        #pragma unroll
        for (int j = 0; j < 4; ++j) {
          float s_ = acc[i][j][r] * scale;
          s_ = (ck[j] == cq[i][r]) ? s_ : -1e30f;
          s0[j] = s_;
          m = fmaxf(m, s_);
        }
        m = fmaxf(m, __shfl_xor(m, 1));
        m = fmaxf(m, __shfl_xor(m, 2));
        m = fmaxf(m, __shfl_xor(m, 4));
        m = fmaxf(m, __shfl_xor(m, 8));
        float sum = 0.f;
        #pragma unroll
        for (int j = 0; j < 4; ++j) { s0[j] = __expf(s0[j] - m); sum += s0[j]; }
        sum += __shfl_xor(sum, 1);
        sum += __shfl_xor(sum, 2);
        sum += __shfl_xor(sum, 4);
        sum += __shfl_xor(sum, 8);
        float inv = 1.0f / sum;
        int row = 16 * i + 4 * l4 + r;
        #pragma unroll
        for (int j = 0; j < 4; ++j)
          pw[row * 72 + 16 * j + l15] = f2bf(s0[j] * inv);
      }
    }

    // ---- O = P V : 16 MFMA ----
    f32x4 oacc[4][2];
    #pragma unroll
    for (int i = 0; i < 4; ++i)
      #pragma unroll
      for (int jn = 0; jn < 2; ++jn) oacc[i][jn] = (f32x4){0.f, 0.f, 0.f, 0.f};
    #pragma unroll
    for (int ks = 0; ks < 2; ++ks) {
      bf16x8 pf[4];
      #pragma unroll
      for (int i = 0; i < 4; ++i)
        pf[i] = *(const bf16x8*)&pw[(16 * i + l15) * 72 + ks * 32 + l4 * 8];
      #pragma unroll
      for (int i = 0; i < 4; ++i)
        #pragma unroll
        for (int jn = 0; jn < 2; ++jn)
          oacc[i][jn] = __builtin_amdgcn_mfma_f32_16x16x32_bf16(pf[i], vf[ks][jn], oacc[i][jn], 0, 0, 0);
    }

    // ---- store O rows < 49 ----
    #pragma unroll
    for (int i = 0; i < 4; ++i) {
      int row = 16 * i + 4 * l4;
      #pragma unroll
      for (int jn = 0; jn < 2; ++jn)
        #pragma unroll
        for (int r = 0; r < 4; ++r)
          if (row + r < 49)
            out[((size_t)win * 49 + row + r) * 512 + head * 32 + jn * 16 + l15] =
                f2bf(oacc[i][jn][r]);
    }
  }
}

extern "C" void kernel_launch(void* const* d_in, const int* in_sizes, int n_in,
                              void* d_out, int out_size, void* d_ws, size_t ws_size,
                              hipStream_t stream) {
  const float* x     = (const float*)d_in[0];
  const float* ln1w  = (const float*)d_in[1];
  const float* ln1b  = (const float*)d_in[2];
  const float* qkvw  = (const float*)d_in[3];
  const float* qkvb  = (const float*)d_in[4];
  const float* projw = (const float*)d_in[5];
  const float* projb = (const float*)d_in[6];
  const float* ln2w  = (const float*)d_in[7];
  const float* ln2b  = (const float*)d_in[8];
  const float* fc1w  = (const float*)d_in[9];
  const float* fc1b  = (const float*)d_in[10];
  const float* fc2w  = (const float*)d_in[11];
  const float* fc2b  = (const float*)d_in[12];
  float* outF = (float*)d_out;

  u16* wsu     = (u16*)d_ws;
  u16* qkv_wt  = wsu;                         // 512*1536 bf16
  u16* proj_wt = qkv_wt  + 512 * 1536;        // 512*512
  u16* fc1_wt  = proj_wt + 512 * 512;         // 1024 rows x 512 (N,K)
  u16* fc2_wt  = fc1_wt  + 512 * 1024;        // 512 rows x 1024
  u16* xw      = fc2_wt  + 1024 * 512;        // LTOK*512 bf16 (LN1 out; later attnO; later LN2 out)
  u16* qkvB    = xw + (size_t)LTOK * 512;     // LTOK*1536 bf16 (later fc1 out z1)
  u16* attnO   = xw;                          // alias: xw dead after qkv GEMM
  u16* z_in    = xw;                          // alias: attnO dead after proj GEMM
  u16* z1      = qkvB;                        // alias: qkvB dead after attn
  float* x2    = outF;                        // f32 residual stream lives in d_out

  transpose_kernel<<<dim3(1536 / 32, 512 / 32), 256, 0, stream>>>(qkvw, qkv_wt, 512, 1536);
  transpose_kernel<<<dim3(512 / 32, 512 / 32),  256, 0, stream>>>(projw, proj_wt, 512, 512);
  transpose_kernel<<<dim3(1024 / 32, 512 / 32), 256, 0, stream>>>(fc1w, fc1_wt, 512, 1024);
  transpose_kernel<<<dim3(512 / 32, 1024 / 32), 256, 0, stream>>>(fc2w, fc2_wt, 1024, 512);

  ln1_kernel<<<LTOK / 4, 256, 0, stream>>>(x, ln1w, ln1b, xw);

  gemm_kernel<0, 1536, 512><<<dim3(196, 12), 256, 0, stream>>>(xw, qkv_wt, qkvb, qkvB, nullptr);

  attn_kernel<<<512, 256, 0, stream>>>(qkvB, attnO);

  gemm_kernel<1, 512, 512><<<dim3(196, 4), 256, 0, stream>>>(attnO, proj_wt, projb, x2, x);

  ln2_kernel<<<LTOK / 4, 256, 0, stream>>>(x2, ln2w, ln2b, z_in);

  gemm_kernel<2, 1024, 512><<<dim3(196, 8), 256, 0, stream>>>(z_in, fc1_wt, fc1b, z1, nullptr);

  gemm_kernel<3, 512, 1024><<<dim3(196, 4), 256, 0, stream>>>(z1, fc2_wt, fc2b, outF, x2);
}

// Round 7
// 420.475 us; speedup vs baseline: 1.3865x; 1.1170x over previous
//
#include <hip/hip_runtime.h>

typedef unsigned short u16;
typedef unsigned short u16x8 __attribute__((ext_vector_type(8)));
typedef __bf16         bf16x8 __attribute__((ext_vector_type(8)));
typedef float          f32x4  __attribute__((ext_vector_type(4)));

#define DIM 512
#define LTOK 25088   // 8 * 56 * 56

__device__ __forceinline__ float bf2f(u16 u) {
  union { unsigned int i; float f; } c; c.i = ((unsigned int)u) << 16; return c.f;
}
__device__ __forceinline__ u16 f2bf(float f) {
  union { float f; unsigned int i; } c; c.f = f;
  unsigned int i = c.i;
  return (u16)((i + 0x7FFFu + ((i >> 16) & 1u)) >> 16);
}
__device__ __forceinline__ float gelu_tanh(float x) {
  // 0.5*x*(1+tanh(y)) == x*sigmoid(2y); 2*0.7978845608 = 1.5957691216, *0.044715 -> 0.0713548156
  float x2 = x * x;
  float y2 = x * (1.5957691216057308f + 0.0713548162726f * x2);
  return x / (1.0f + __expf(-y2));
}
// async global->LDS, 16B per lane; LDS dest must be wave-uniform
__device__ __forceinline__ void gload16(const u16* g, u16* l) {
  __builtin_amdgcn_global_load_lds(
      (__attribute__((address_space(1))) void*)(u16*)g,
      (__attribute__((address_space(3))) void*)l,
      16, 0, 0);
}
// window-major row -> natural token index (same map for partition source and reverse dest)
__device__ __forceinline__ int rowToToken(int row) {
  int win = row / 49, t = row - win * 49;
  int b = win >> 6, wi = win & 63;
  int hr = (wi >> 3) * 7 + t / 7;
  int wr = (wi & 7) * 7 + t % 7;
  int hs = hr + 3; if (hs >= 56) hs -= 56;
  int ws2 = wr + 3; if (ws2 >= 56) ws2 -= 56;
  return b * 3136 + hs * 56 + ws2;
}

// ---------------- LN1: f32 in (natural order, rolled+permuted source), bf16 out (window-major) ----
__global__ __launch_bounds__(256) void ln1_kernel(const float* __restrict__ x,
    const float* __restrict__ w, const float* __restrict__ b, u16* __restrict__ out) {
  int r = blockIdx.x * 4 + (threadIdx.x >> 6);   // output row, window-major
  int lane = threadIdx.x & 63;
  int tok = rowToToken(r);
  const float* src = x + (size_t)tok * DIM + lane * 8;
  float v[8]; float s = 0.f, ss = 0.f;
  f32x4 v0 = *(const f32x4*)(src);
  f32x4 v1 = *(const f32x4*)(src + 4);
  #pragma unroll
  for (int j = 0; j < 4; ++j) { v[j] = v0[j]; v[j + 4] = v1[j]; }
  #pragma unroll
  for (int j = 0; j < 8; ++j) { s += v[j]; ss += v[j] * v[j]; }
  #pragma unroll
  for (int off = 32; off > 0; off >>= 1) { s += __shfl_xor(s, off); ss += __shfl_xor(ss, off); }
  float mean = s * (1.0f / 512.0f);
  float var  = ss * (1.0f / 512.0f) - mean * mean;
  float rstd = rsqrtf(var + 1e-5f);
  f32x4 w0 = *(const f32x4*)(w + lane * 8), w1 = *(const f32x4*)(w + lane * 8 + 4);
  f32x4 b0 = *(const f32x4*)(b + lane * 8), b1 = *(const f32x4*)(b + lane * 8 + 4);
  u16x8 o;
  #pragma unroll
  for (int j = 0; j < 4; ++j) {
    o[j]     = f2bf((v[j]     - mean) * rstd * w0[j] + b0[j]);
    o[j + 4] = f2bf((v[j + 4] - mean) * rstd * w1[j] + b1[j]);
  }
  *(u16x8*)(out + (size_t)r * DIM + lane * 8) = o;
}

// ---------------- LN2: f32 in (natural order), bf16 out ----------------
__global__ __launch_bounds__(256) void ln2_kernel(const float* __restrict__ x2,
    const float* __restrict__ w, const float* __restrict__ b, u16* __restrict__ out) {
  int r = blockIdx.x * 4 + (threadIdx.x >> 6);
  int lane = threadIdx.x & 63;
  const float* src = x2 + (size_t)r * DIM + lane * 8;
  float v[8]; float s = 0.f, ss = 0.f;
  f32x4 v0 = *(const f32x4*)(src);
  f32x4 v1 = *(const f32x4*)(src + 4);
  #pragma unroll
  for (int j = 0; j < 4; ++j) { v[j] = v0[j]; v[j + 4] = v1[j]; }
  #pragma unroll
  for (int j = 0; j < 8; ++j) { s += v[j]; ss += v[j] * v[j]; }
  #pragma unroll
  for (int off = 32; off > 0; off >>= 1) { s += __shfl_xor(s, off); ss += __shfl_xor(ss, off); }
  float mean = s * (1.0f / 512.0f);
  float var  = ss * (1.0f / 512.0f) - mean * mean;
  float rstd = rsqrtf(var + 1e-5f);
  f32x4 w0 = *(const f32x4*)(w + lane * 8), w1 = *(const f32x4*)(w + lane * 8 + 4);
  f32x4 b0 = *(const f32x4*)(b + lane * 8), b1 = *(const f32x4*)(b + lane * 8 + 4);
  u16x8 o;
  #pragma unroll
  for (int j = 0; j < 4; ++j) {
    o[j]     = f2bf((v[j]     - mean) * rstd * w0[j] + b0[j]);
    o[j + 4] = f2bf((v[j + 4] - mean) * rstd * w1[j] + b1[j]);
  }
  *(u16x8*)(out + (size_t)r * DIM + lane * 8) = o;
}

// ---------------- weight transpose+cast: f32 (K,N) -> bf16 (N,K) ----------------
__global__ __launch_bounds__(256) void transpose_kernel(const float* __restrict__ in,
    u16* __restrict__ out, int K, int N) {
  __shared__ u16 tile[32][33];
  int tx = threadIdx.x & 31, ty = threadIdx.x >> 5;
  int n0 = blockIdx.x * 32, k0 = blockIdx.y * 32;
  #pragma unroll
  for (int r = 0; r < 4; ++r) {
    int kr = ty + r * 8;
    tile[kr][tx] = f2bf(in[(size_t)(k0 + kr) * N + n0 + tx]);
  }
  __syncthreads();
  #pragma unroll
  for (int r = 0; r < 4; ++r) {
    int nr = ty + r * 8;
    out[(size_t)(n0 + nr) * K + k0 + tx] = tile[tx][nr];
  }
}

// ---------------- GEMM: C(MxN) = A(MxK) * Bt(NxK)^T + bias(f32), fused epilogues ----------------
// Double-buffered LDS, stage(t+1) issued before compute(t), ONE barrier per K-step.
// LDS XOR-swizzle (rule 21): linear gload_lds dest + inverse-swizzled global source + swizzled ds_read.
// MODE 0: -> bf16 row-major (qkv). MODE 1: window-reverse + f32 residual -> f32.
// MODE 2: gelu -> bf16 (fc1).     MODE 3: + f32 residual -> f32 (may alias resF, same-index RMW).
template<int MODE, int N, int KD>
__global__ __launch_bounds__(256) void gemm_kernel(
    const u16* __restrict__ A, const u16* __restrict__ Bt,
    const float* __restrict__ bias, void* outp,
    const float* resF) {
  __shared__ __align__(16) u16 lA[2][8192];   // 2 x 128x64 bf16
  __shared__ __align__(16) u16 lB[2][8192];
  int tid = threadIdx.x;
  int lane = tid & 63, wid = tid >> 6;
  int wm = wid >> 1, wn = wid & 1;
  int m0 = blockIdx.x * 128, n0 = blockIdx.y * 128;
  int l15 = lane & 15, l4 = lane >> 4;
  f32x4 acc[4][4];
  #pragma unroll
  for (int i = 0; i < 4; ++i)
    #pragma unroll
    for (int j = 0; j < 4; ++j) acc[i][j] = (f32x4){0.f, 0.f, 0.f, 0.f};

  // stage one 128x64 K-tile of A and B into buffer buf (source inverse-swizzled)
  auto stage = [&](int buf, int k0) {
    #pragma unroll
    for (int is = 0; is < 4; ++is) {
      int e = is * 2048 + tid * 8;             // linear element slot in tile (row-major, k inner)
      int mm = e >> 6;
      int kk = (e & 63) ^ ((mm & 7) << 3);     // inverse swizzle on source column
      gload16(A  + (size_t)(m0 + mm) * KD + k0 + kk, &lA[buf][is * 2048 + wid * 512]);
      gload16(Bt + (size_t)(n0 + mm) * KD + k0 + kk, &lB[buf][is * 2048 + wid * 512]);
    }
  };
  // MFMA over one staged K-tile (swizzled ds_read addresses)
  auto compute = [&](int buf) {
    #pragma unroll
    for (int ks = 0; ks < 2; ++ks) {
      bf16x8 af[4], bfv[4];
      int ksw = (ks * 32 + l4 * 8) ^ ((l15 & 7) << 3);
      #pragma unroll
      for (int i = 0; i < 4; ++i)
        af[i] = *(const bf16x8*)&lA[buf][(wm * 64 + i * 16 + l15) * 64 + ksw];
      #pragma unroll
      for (int j = 0; j < 4; ++j)
        bfv[j] = *(const bf16x8*)&lB[buf][(wn * 64 + j * 16 + l15) * 64 + ksw];
      __builtin_amdgcn_s_setprio(1);
      #pragma unroll
      for (int i = 0; i < 4; ++i)
        #pragma unroll
        for (int j = 0; j < 4; ++j)
          acc[i][j] = __builtin_amdgcn_mfma_f32_16x16x32_bf16(af[i], bfv[j], acc[i][j], 0, 0, 0);
      __builtin_amdgcn_s_setprio(0);
    }
  };

  stage(0, 0);
  __syncthreads();                 // drains prologue loads
  int cur = 0;
  for (int t = 0; t < KD / 64 - 1; ++t) {
    stage(cur ^ 1, (t + 1) * 64);  // issue next-tile loads BEFORE compute
    compute(cur);                  // latency hides under MFMA+ds_read
    __syncthreads();               // single barrier/K-step; drains the in-flight stage
    cur ^= 1;
  }
  compute(cur);

  #pragma unroll
  for (int i = 0; i < 4; ++i) {
    #pragma unroll
    for (int j = 0; j < 4; ++j) {
      int col = n0 + wn * 64 + j * 16 + l15;
      float bcol = bias[col];
      #pragma unroll
      for (int r = 0; r < 4; ++r) {
        int row = m0 + wm * 64 + i * 16 + l4 * 4 + r;
        float v = acc[i][j][r] + bcol;
        if constexpr (MODE == 0) {
          ((u16*)outp)[(size_t)row * N + col] = f2bf(v);
        } else if constexpr (MODE == 1) {
          int tok = rowToToken(row);
          size_t idx = (size_t)tok * DIM + col;
          ((float*)outp)[idx] = v + resF[idx];
        } else if constexpr (MODE == 2) {
          ((u16*)outp)[(size_t)row * N + col] = f2bf(gelu_tanh(v));
        } else {  // MODE 3
          size_t idx = (size_t)row * N + col;
          ((float*)outp)[idx] = v + resF[idx];
        }
      }
    }
  }
}

// ---------------- MFMA window attention: 1 block per window, 4 waves, 4 heads/wave ----------------
__global__ __launch_bounds__(256) void attn_kernel(const u16* __restrict__ qkv,
                                                   u16* __restrict__ out) {
  int win = blockIdx.x;
  int wi = win & 63;
  int tid = threadIdx.x, lane = tid & 63, wid = tid >> 6;
  int l15 = lane & 15, l4 = lane >> 4;
  __shared__ int codes[49];
  __shared__ __align__(16) u16 plds[4][64 * 72];
  if (tid < 49) {
    int hr = (wi >> 3) * 7 + tid / 7;
    int wr = (wi & 7) * 7 + tid % 7;
    int rh = (hr < 49) ? 0 : (hr < 53 ? 1 : 2);
    int rw = (wr < 49) ? 0 : (wr < 53 ? 1 : 2);
    codes[tid] = rh * 3 + rw;
  }
  __syncthreads();
  int ck[4], cq[4][4];
  #pragma unroll
  for (int j = 0; j < 4; ++j) {
    int c = 16 * j + l15;
    ck[j] = (c < 49) ? codes[c] : -1;
  }
  #pragma unroll
  for (int i = 0; i < 4; ++i)
    #pragma unroll
    for (int r = 0; r < 4; ++r) {
      int row = 16 * i + 4 * l4 + r;
      cq[i][r] = codes[row < 49 ? row : 48];
    }
  size_t wbase = (size_t)win * 49 * 1536;
  u16* pw = plds[wid];
  const float scale = 0.17677669529663687f;   // 1/sqrt(32)

  for (int hh = 0; hh < 4; ++hh) {
    int head = wid * 4 + hh;
    size_t hoff = wbase + (size_t)head * 32;

    bf16x8 vf[2][2];
    #pragma unroll
    for (int ks = 0; ks < 2; ++ks)
      #pragma unroll
      for (int jn = 0; jn < 2; ++jn) {
        u16x8 tmp;
        #pragma unroll
        for (int j = 0; j < 8; ++j) {
          int tok = ks * 32 + l4 * 8 + j; tok = tok < 49 ? tok : 48;
          tmp[j] = qkv[hoff + (size_t)tok * 1536 + 1024 + jn * 16 + l15];
        }
        vf[ks][jn] = __builtin_bit_cast(bf16x8, tmp);
      }

    bf16x8 qf[4], kf[4];
    #pragma unroll
    for (int i = 0; i < 4; ++i) {
      int tr = 16 * i + l15; tr = tr < 49 ? tr : 48;
      qf[i] = *(const bf16x8*)(qkv + hoff + (size_t)tr * 1536 + l4 * 8);
      kf[i] = *(const bf16x8*)(qkv + hoff + (size_t)tr * 1536 + 512 + l4 * 8);
    }

    f32x4 acc[4][4];
    #pragma unroll
    for (int i = 0; i < 4; ++i)
      #pragma unroll
      for (int j = 0; j < 4; ++j) acc[i][j] = (f32x4){0.f, 0.f, 0.f, 0.f};
    #pragma unroll
    for (int i = 0; i < 4; ++i)
      #pragma unroll
      for (int j = 0; j < 4; ++j)
        acc[i][j] = __builtin_amdgcn_mfma_f32_16x16x32_bf16(qf[i], kf[j], acc[i][j], 0, 0, 0);

    #pragma unroll
    for (int i = 0; i < 4; ++i) {
      #pragma unroll
      for (int r = 0; r < 4; ++r) {
        float s0[4];
        float m = -1e30f;
        #pragma unroll
        for (int j = 0; j < 4; ++j) {
          float s_ = acc[i][j][r] * scale;
          s_ = (ck[j] == cq[i][r]) ? s_ : -1e30f;
          s0[j] = s_;
          m = fmaxf(m, s_);
        }
        m = fmaxf(m, __shfl_xor(m, 1));
        m = fmaxf(m, __shfl_xor(m, 2));
        m = fmaxf(m, __shfl_xor(m, 4));
        m = fmaxf(m, __shfl_xor(m, 8));
        float sum = 0.f;
        #pragma unroll
        for (int j = 0; j < 4; ++j) { s0[j] = __expf(s0[j] - m); sum += s0[j]; }
        sum += __shfl_xor(sum, 1);
        sum += __shfl_xor(sum, 2);
        sum += __shfl_xor(sum, 4);
        sum += __shfl_xor(sum, 8);
        float inv = 1.0f / sum;
        int row = 16 * i + 4 * l4 + r;
        #pragma unroll
        for (int j = 0; j < 4; ++j)
          pw[row * 72 + 16 * j + l15] = f2bf(s0[j] * inv);
      }
    }

    f32x4 oacc[4][2];
    #pragma unroll
    for (int i = 0; i < 4; ++i)
      #pragma unroll
      for (int jn = 0; jn < 2; ++jn) oacc[i][jn] = (f32x4){0.f, 0.f, 0.f, 0.f};
    #pragma unroll
    for (int ks = 0; ks < 2; ++ks) {
      bf16x8 pf[4];
      #pragma unroll
      for (int i = 0; i < 4; ++i)
        pf[i] = *(const bf16x8*)&pw[(16 * i + l15) * 72 + ks * 32 + l4 * 8];
      #pragma unroll
      for (int i = 0; i < 4; ++i)
        #pragma unroll
        for (int jn = 0; jn < 2; ++jn)
          oacc[i][jn] = __builtin_amdgcn_mfma_f32_16x16x32_bf16(pf[i], vf[ks][jn], oacc[i][jn], 0, 0, 0);
    }

    #pragma unroll
    for (int i = 0; i < 4; ++i) {
      int row = 16 * i + 4 * l4;
      #pragma unroll
      for (int jn = 0; jn < 2; ++jn)
        #pragma unroll
        for (int r = 0; r < 4; ++r)
          if (row + r < 49)
            out[((size_t)win * 49 + row + r) * 512 + head * 32 + jn * 16 + l15] =
                f2bf(oacc[i][jn][r]);
    }
  }
}

extern "C" void kernel_launch(void* const* d_in, const int* in_sizes, int n_in,
                              void* d_out, int out_size, void* d_ws, size_t ws_size,
                              hipStream_t stream) {
  const float* x     = (const float*)d_in[0];
  const float* ln1w  = (const float*)d_in[1];
  const float* ln1b  = (const float*)d_in[2];
  const float* qkvw  = (const float*)d_in[3];
  const float* qkvb  = (const float*)d_in[4];
  const float* projw = (const float*)d_in[5];
  const float* projb = (const float*)d_in[6];
  const float* ln2w  = (const float*)d_in[7];
  const float* ln2b  = (const float*)d_in[8];
  const float* fc1w  = (const float*)d_in[9];
  const float* fc1b  = (const float*)d_in[10];
  const float* fc2w  = (const float*)d_in[11];
  const float* fc2b  = (const float*)d_in[12];
  float* outF = (float*)d_out;

  u16* wsu     = (u16*)d_ws;
  u16* qkv_wt  = wsu;                         // 512*1536 bf16
  u16* proj_wt = qkv_wt  + 512 * 1536;        // 512*512
  u16* fc1_wt  = proj_wt + 512 * 512;         // 1024 rows x 512 (N,K)
  u16* fc2_wt  = fc1_wt  + 512 * 1024;        // 512 rows x 1024
  u16* xw      = fc2_wt  + 1024 * 512;        // LTOK*512 bf16 (LN1 out; later attnO; later LN2 out)
  u16* qkvB    = xw + (size_t)LTOK * 512;     // LTOK*1536 bf16 (later fc1 out z1)
  u16* attnO   = xw;                          // alias: xw dead after qkv GEMM
  u16* z_in    = xw;                          // alias: attnO dead after proj GEMM
  u16* z1      = qkvB;                        // alias: qkvB dead after attn
  float* x2    = outF;                        // f32 residual stream lives in d_out

  transpose_kernel<<<dim3(1536 / 32, 512 / 32), 256, 0, stream>>>(qkvw, qkv_wt, 512, 1536);
  transpose_kernel<<<dim3(512 / 32, 512 / 32),  256, 0, stream>>>(projw, proj_wt, 512, 512);
  transpose_kernel<<<dim3(1024 / 32, 512 / 32), 256, 0, stream>>>(fc1w, fc1_wt, 512, 1024);
  transpose_kernel<<<dim3(512 / 32, 1024 / 32), 256, 0, stream>>>(fc2w, fc2_wt, 1024, 512);

  ln1_kernel<<<LTOK / 4, 256, 0, stream>>>(x, ln1w, ln1b, xw);

  gemm_kernel<0, 1536, 512><<<dim3(196, 12), 256, 0, stream>>>(xw, qkv_wt, qkvb, qkvB, nullptr);

  attn_kernel<<<512, 256, 0, stream>>>(qkvB, attnO);

  gemm_kernel<1, 512, 512><<<dim3(196, 4), 256, 0, stream>>>(attnO, proj_wt, projb, x2, x);

  ln2_kernel<<<LTOK / 4, 256, 0, stream>>>(x2, ln2w, ln2b, z_in);

  gemm_kernel<2, 1024, 512><<<dim3(196, 8), 256, 0, stream>>>(z_in, fc1_wt, fc1b, z1, nullptr);

  gemm_kernel<3, 512, 1024><<<dim3(196, 4), 256, 0, stream>>>(z1, fc2_wt, fc2b, outF, x2);
}